// Round 4
// baseline (176.150 us; speedup 1.0000x reference)
//
#include <hip/hip_runtime.h>

// x (8,3,40,128,128) f32, W (16,3,3,3,3) f32, b (16) f32.
// conv3d VALID -> softmax(C=16) -> 4x4x4 truncating maxpool -> (8,16,9,31,31).
//
// R4: (a) pad LDS depth dim 6->7 (stride coprime with 32 banks: R3 had 4.9M
//     bank-conflict cycles from stride-6); (b) build each packed depth-pair
//     directly via ds_read2_b32-style two-offset LDS reads -> aligned VGPR
//     pairs, no packing movs; (c) force v_pk_fma_f32 via inline asm with the
//     weight as an SGPR-pair source; (d) weights/bias pre-scaled by log2(e)
//     so softmax uses raw v_exp_f32 (base-2), saving the per-exp multiply.

typedef float v2f __attribute__((ext_vector_type(2)));

#define LOG2E 1.44269504088896340736f

__global__ void dup_weights(const float* __restrict__ W, float* __restrict__ wd) {
    int i = blockIdx.x * 256 + threadIdx.x;     // 81*16 = 1296 entries
    if (i < 81 * 16) {
        int oc  = i & 15;
        int tap = i >> 4;                        // ((ci*3+kd)*9 + t)
        int ci = tap / 27, r = tap % 27, kd = r / 9, t = r % 9;
        float w = W[((oc * 3 + ci) * 3 + kd) * 9 + t] * LOG2E;
        wd[2 * i]     = w;
        wd[2 * i + 1] = w;
    }
}

#define PKFMA(acc, xx, ww) \
    asm("v_pk_fma_f32 %0, %1, %2, %0" : "+v"(acc) : "v"(xx), "s"(ww))

template<int PAIRED>
__global__ __launch_bounds__(256, 2)
void conv_softmax_pool(const float* __restrict__ x,
                       const float* __restrict__ W,
                       const float* __restrict__ bias,
                       const v2f* __restrict__ wd,
                       float* __restrict__ out) {
    const int bid = blockIdx.x;
    const int wt  = bid & 1;            // w-tile: 0 -> wo 0..15, 1 -> wo 16..30
    const int ho  = (bid >> 1) % 31;
    const int dpo = (bid / 62) % 9;
    const int b   = bid / 558;          // 558 = 2*31*9

    const int w0 = wt * 64;
    const int h0 = ho * 4;
    const int d0 = dpo * 4;
    const int activeW = wt ? 60 : 64;

    __shared__ float xs[3][6][66][7];   // [ci][h][w][d(+pad)]  33.3 KB
    __shared__ float red[4][16][17];    // 4.25 KB

    const int tid = threadIdx.x;

    // ---- stage x tile (read coalesced in w, write d-innermost, stride 7) ----
    const size_t xbase = (size_t)b * (3ull * 40 * 128 * 128);
    for (int idx = tid; idx < 3 * 6 * 6 * 66; idx += 256) {
        int w = idx % 66;
        int t = idx / 66;
        int h = t % 6;  t /= 6;
        int d = t % 6;
        int ci = t / 6;
        int gw = w0 + w;
        float v = 0.0f;
        if (gw < 128)
            v = x[xbase + ((size_t)ci * 40 + (d0 + d)) * 16384
                        + (size_t)(h0 + h) * 128 + gw];
        xs[ci][h][w][d] = v;
    }
    __syncthreads();

    const int tx = tid & 63;
    const int ty = tid >> 6;

    v2f ya[16], yb[16];                 // depths (d0,d0+1) and (d0+2,d0+3)
    #pragma unroll
    for (int c = 0; c < 16; ++c) {
        float bb = bias[c] * (PAIRED ? LOG2E : 1.0f);
        ya[c] = (v2f){bb, bb};
        yb[c] = ya[c];
    }

    #pragma unroll 1
    for (int ci = 0; ci < 3; ++ci) {
        #pragma unroll
        for (int kh = 0; kh < 3; ++kh) {
            #pragma unroll
            for (int kw = 0; kw < 3; ++kw) {
                const float* xp = &xs[ci][ty + kh][tx + kw][0];
                // 5 unique depth-pairs, each one two-offset LDS read -> VGPR pair
                v2f a0, a1, s23, b1, b2;
                a0.x  = xp[0]; a0.y  = xp[1];
                a1.x  = xp[1]; a1.y  = xp[2];
                s23.x = xp[2]; s23.y = xp[3];
                b1.x  = xp[3]; b1.y  = xp[4];
                b2.x  = xp[4]; b2.y  = xp[5];

                const int t = kh * 3 + kw;
                #pragma unroll
                for (int kd = 0; kd < 3; ++kd) {
                    v2f xa = (kd == 0) ? a0  : (kd == 1) ? a1 : s23;
                    v2f xb = (kd == 0) ? s23 : (kd == 1) ? b1 : b2;
                    if constexpr (PAIRED) {
                        const v2f* wp = wd + ((ci * 3 + kd) * 9 + t) * 16;
                        #pragma unroll
                        for (int oc = 0; oc < 16; ++oc) {
                            v2f ww = wp[oc];                 // uniform -> s_load pair
                            PKFMA(ya[oc], xa, ww);
                            PKFMA(yb[oc], xb, ww);
                        }
                    } else {
                        #pragma unroll
                        for (int oc = 0; oc < 16; ++oc) {
                            float w = W[((oc * 3 + ci) * 3 + kd) * 9 + t];
                            v2f w2 = (v2f){w, w};
                            ya[oc] = __builtin_elementwise_fma(xa, w2, ya[oc]);
                            yb[oc] = __builtin_elementwise_fma(xb, w2, yb[oc]);
                        }
                    }
                }
            }
        }
    }

    // packed softmax over 16 channels for both depth pairs (base-2 if PAIRED)
    v2f ma = ya[0], mb = yb[0];
    #pragma unroll
    for (int c = 1; c < 16; ++c) {
        ma = __builtin_elementwise_max(ma, ya[c]);
        mb = __builtin_elementwise_max(mb, yb[c]);
    }
    v2f sa = (v2f){0.f, 0.f}, sb = sa;
    #pragma unroll
    for (int c = 0; c < 16; ++c) {
        v2f ea = ya[c] - ma, eb = yb[c] - mb;
        if constexpr (PAIRED) {
            ya[c] = (v2f){__builtin_amdgcn_exp2f(ea.x), __builtin_amdgcn_exp2f(ea.y)};
            yb[c] = (v2f){__builtin_amdgcn_exp2f(eb.x), __builtin_amdgcn_exp2f(eb.y)};
        } else {
            ya[c] = (v2f){__expf(ea.x), __expf(ea.y)};
            yb[c] = (v2f){__expf(eb.x), __expf(eb.y)};
        }
        sa += ya[c]; sb += yb[c];
    }
    v2f inva = (v2f){__builtin_amdgcn_rcpf(sa.x), __builtin_amdgcn_rcpf(sa.y)};
    v2f invb = (v2f){__builtin_amdgcn_rcpf(sb.x), __builtin_amdgcn_rcpf(sb.y)};

    // depth pool + w pool (groups of 4 lanes)
    float pmax[16];
    #pragma unroll
    for (int c = 0; c < 16; ++c) {
        v2f pa = ya[c] * inva, pb = yb[c] * invb;
        v2f m = __builtin_elementwise_max(pa, pb);
        float v = fmaxf(m.x, m.y);
        v = fmaxf(v, __shfl_xor(v, 1));
        v = fmaxf(v, __shfl_xor(v, 2));
        pmax[c] = v;
    }
    if (tx < activeW && (tx & 3) == 0) {
        int wc = tx >> 2;
        #pragma unroll
        for (int c = 0; c < 16; ++c) red[ty][wc][c] = pmax[c];
    }
    __syncthreads();

    // reduce over 4 h-rows, write coalesced
    {
        int ch = tid >> 4;
        int wc = tid & 15;
        int wo = wt * 16 + wc;
        if (wo < 31) {
            float v =         red[0][wc][ch];
            v = fmaxf(v, red[1][wc][ch]);
            v = fmaxf(v, red[2][wc][ch]);
            v = fmaxf(v, red[3][wc][ch]);
            out[(((size_t)b * 16 + ch) * 9 + dpo) * 961 + (size_t)ho * 31 + wo] = v;
        }
    }
}

extern "C" void kernel_launch(void* const* d_in, const int* in_sizes, int n_in,
                              void* d_out, int out_size, void* d_ws, size_t ws_size,
                              hipStream_t stream) {
    const float* x  = (const float*)d_in[0];
    const float* W  = (const float*)d_in[1];
    const float* bb = (const float*)d_in[2];
    float* out = (float*)d_out;

    const int blocks = 8 * 9 * 31 * 2;  // 4464
    const size_t WBYTES = 81 * 16 * 2 * sizeof(float);  // 10368 B

    if (ws_size >= WBYTES) {
        hipLaunchKernelGGL(dup_weights, dim3(6), dim3(256), 0, stream,
                           W, (float*)d_ws);
        hipLaunchKernelGGL((conv_softmax_pool<1>), dim3(blocks), dim3(256), 0, stream,
                           x, W, bb, (const v2f*)d_ws, out);
    } else {
        hipLaunchKernelGGL((conv_softmax_pool<0>), dim3(blocks), dim3(256), 0, stream,
                           x, W, bb, (const v2f*)d_ws, out);
    }
}

// Round 5
// 110.954 us; speedup vs baseline: 1.5876x; 1.5876x over previous
//
#include <hip/hip_runtime.h>
#include <stdint.h>

// x (8,3,40,128,128) f32, W (16,3,3,3,3) f32, b (16) f32.
// conv3d VALID -> softmax(C=16) -> 4x4x4 truncating maxpool -> (8,16,9,31,31).
//
// R5: conv via MFMA 16x16x32 bf16.
//  - x stored in LDS as packed u32 {bf16_hi | bf16_lo<<16}; K enumerates
//    (tap, hi/lo) pairs; B carries the same bf16 weight in both halves of a
//    pair => sum reconstructs exact-x * bf16(w). Only W-rounding error.
//  - K-tile = 4 planes (ci,kd,kh) x {kw0,kw1,kw2,pad}; 7 tiles cover 27 planes.
//    A-gather: 3 ds_read_b32 per tile at per-lane plane offsets (separable
//    addressing); pad slot zeroed (never NaN), pad B entries are 0.
//  - B fragments precomputed in d_ws in the exact (laneGroup g, reg r) slot
//    convention used by the A gather (k-permutation invariance makes the
//    hw k-map uncertainty cancel).
//  - Softmax over oc: C/D layout col=lane&15=oc, rows=4*(lane>>4)+reg; 16-lane
//    DPP row_ror rotate-allreduce (VALU only). w-pool = max over 4 regs in
//    lane; d/h-pool = running max across the 16 (dd,hh) M-tiles.

typedef float f4 __attribute__((ext_vector_type(4)));
typedef short s8v __attribute__((ext_vector_type(8)));

#define LOG2E 1.44269504088896340736f

__device__ __host__ inline uint32_t bf16rnd(float x) {
    uint32_t u = __float_as_uint(x);
    return (u + 0x7FFFu + ((u >> 16) & 1u)) >> 16;
}

// B-fragment table: wd[(T*64 + lane)*4 + r] = dup16(bf16(W[n][ci][kd][kh][r]*log2e))
// with n = lane&15, plane p = 4T + (lane>>4) -> (ci,kd,kh); 0 for p>=27 or r==3.
__global__ void build_bfrag(const float* __restrict__ W, uint32_t* __restrict__ wd) {
    int idx = blockIdx.x * 256 + threadIdx.x;       // 7*64*4 = 1792
    if (idx < 1792) {
        int r = idx & 3, l = (idx >> 2) & 63, T = idx >> 8;
        int p = 4 * T + (l >> 4), n = l & 15;
        uint32_t v = 0;
        if (p < 27 && r < 3) {
            int ci = p / 9, kd = (p / 3) % 3, kh = p % 3;
            float w = W[(((n * 3 + ci) * 3 + kd) * 3 + kh) * 3 + r] * LOG2E;
            uint32_t h = bf16rnd(w);
            v = (h << 16) | h;
        }
        wd[idx] = v;
    }
}

template<int CTRL>
__device__ inline float dppror(float v) {
    return __int_as_float(__builtin_amdgcn_update_dpp(
        0, __float_as_int(v), CTRL, 0xF, 0xF, true));
}
__device__ inline float allmax16(float v) {   // all-reduce max within 16-lane row
    v = fmaxf(v, dppror<0x121>(v));   // row_ror:1
    v = fmaxf(v, dppror<0x122>(v));   // row_ror:2
    v = fmaxf(v, dppror<0x124>(v));   // row_ror:4
    v = fmaxf(v, dppror<0x128>(v));   // row_ror:8
    return v;
}
__device__ inline float allsum16(float v) {
    v += dppror<0x121>(v);
    v += dppror<0x122>(v);
    v += dppror<0x124>(v);
    v += dppror<0x128>(v);
    return v;
}

__global__ __launch_bounds__(256, 4)
void conv_softmax_pool(const float* __restrict__ x,
                       const float* __restrict__ bias,
                       const uint32_t* __restrict__ wd,
                       float* __restrict__ out) {
    const int bid = blockIdx.x;
    const int wt  = bid & 1;            // w-tile: wo 0..15 / 16..30
    const int ho  = (bid >> 1) % 31;
    const int dpo = (bid / 62) % 9;
    const int b   = bid / 558;          // 558 = 2*31*9

    const int w0 = wt * 64;
    const int h0 = ho * 4;
    const int d0 = dpo * 4;

    __shared__ uint32_t xs[3 * 6 * 6 * 66];     // 28512 B, {hi|lo<<16} pairs

    const int tid = threadIdx.x;

    // ---- stage x tile as bf16 hi/lo pairs ----
    const size_t xbase = (size_t)b * (3ull * 40 * 128 * 128);
    for (int idx = tid; idx < 3 * 6 * 6 * 66; idx += 256) {
        int w = idx % 66;
        int t = idx / 66;
        int h = t % 6;  t /= 6;
        int d = t % 6;
        int ci = t / 6;
        int gw = w0 + w;
        float v = 0.0f;
        if (gw < 128)
            v = x[xbase + ((size_t)ci * 40 + (d0 + d)) * 16384
                        + (size_t)(h0 + h) * 128 + gw];
        uint32_t hb = bf16rnd(v);
        float hf = __uint_as_float(hb << 16);
        uint32_t lb = bf16rnd(v - hf);
        xs[idx] = (lb << 16) | hb;
    }

    // ---- per-lane constants while staging is in flight ----
    const int lane = tid & 63;
    const int wv   = tid >> 6;          // wave id: ww range [16wv, 16wv+16)
    const int m    = lane & 15;         // MFMA row = w position within tile
    const int g    = lane >> 4;         // lane group

    // B fragments (same for all waves)
    s8v bS[7];
    {
        const uint4* wsp = (const uint4*)wd;
        #pragma unroll
        for (int T = 0; T < 7; ++T) {
            uint4 q = wsp[T * 64 + lane];
            bS[T] = __builtin_bit_cast(s8v, q);
        }
    }
    // per-lane static plane byte-offsets (clamped for the single pad plane)
    uint32_t poff[7];
    #pragma unroll
    for (int T = 0; T < 7; ++T) {
        int p = 4 * T + g; if (p > 26) p = 26;   // pad plane: B=0, finite A
        int ci = p / 9, kd = (p / 3) % 3, kh = p % 3;
        poff[T] = (uint32_t)(((ci * 6 + kd) * 6 + kh) * 66) * 4u;
    }
    const float bl = bias[m] * LOG2E;    // oc = m-index only via lane&15
    const char* xsb = (const char*)xs + (uint32_t)(16 * wv + m) * 4u;

    __syncthreads();

    float pool = 0.0f;
    #pragma unroll 1
    for (int dd = 0; dd < 4; ++dd) {
        #pragma unroll 1
        for (int hh = 0; hh < 4; ++hh) {
            const char* dhb = xsb + (uint32_t)((dd * 6 + hh) * 66) * 4u;
            f4 acc = {bl, bl, bl, bl};
            #pragma unroll
            for (int T = 0; T < 7; ++T) {
                const uint32_t* pt = (const uint32_t*)(dhb + poff[T]);
                union { uint32_t u[4]; s8v s; } A;
                A.u[0] = pt[0];          // kw = 0
                A.u[1] = pt[1];          // kw = 1
                A.u[2] = pt[2];          // kw = 2
                A.u[3] = 0;              // pad slot
                acc = __builtin_amdgcn_mfma_f32_16x16x32_bf16(A.s, bS[T], acc, 0, 0, 0);
            }
            // softmax over oc (16-lane groups) for the 4 positions (regs)
            float m0 = allmax16(acc[0]);
            float m1 = allmax16(acc[1]);
            float m2 = allmax16(acc[2]);
            float m3 = allmax16(acc[3]);
            float e0 = __builtin_amdgcn_exp2f(acc[0] - m0);
            float e1 = __builtin_amdgcn_exp2f(acc[1] - m1);
            float e2 = __builtin_amdgcn_exp2f(acc[2] - m2);
            float e3 = __builtin_amdgcn_exp2f(acc[3] - m3);
            float p0 = e0 * __builtin_amdgcn_rcpf(allsum16(e0));
            float p1 = e1 * __builtin_amdgcn_rcpf(allsum16(e1));
            float p2 = e2 * __builtin_amdgcn_rcpf(allsum16(e2));
            float p3 = e3 * __builtin_amdgcn_rcpf(allsum16(e3));
            // w-pool: the 4 regs are positions 4q..4q+3 = one pooled w-cell
            pool = fmaxf(pool, fmaxf(fmaxf(p0, p1), fmaxf(p2, p3)));
        }
    }

    // lane holds pooled value for (oc = lane&15, w-cell q = lane>>4)
    {
        int oc = m;
        int wo = wt * 16 + wv * 4 + g;
        if (wo < 31) {
            out[(((size_t)b * 16 + oc) * 9 + dpo) * 961
                + (size_t)ho * 31 + wo] = pool;
        }
    }
}

extern "C" void kernel_launch(void* const* d_in, const int* in_sizes, int n_in,
                              void* d_out, int out_size, void* d_ws, size_t ws_size,
                              hipStream_t stream) {
    const float* x  = (const float*)d_in[0];
    const float* W  = (const float*)d_in[1];
    const float* bb = (const float*)d_in[2];
    float* out = (float*)d_out;

    hipLaunchKernelGGL(build_bfrag, dim3(7), dim3(256), 0, stream,
                       W, (uint32_t*)d_ws);

    const int blocks = 8 * 9 * 31 * 2;  // 4464
    hipLaunchKernelGGL(conv_softmax_pool, dim3(blocks), dim3(256), 0, stream,
                       x, bb, (const uint32_t*)d_ws, out);
}